// Round 11
// baseline (269.271 us; speedup 1.0000x reference)
//
#include <hip/hip_runtime.h>
#include <hip/hip_bf16.h>
#include <math.h>

#define POST 128
#define NI 129            // T+1
#define NJK 4225          // 65*65
#define NTOT 16512        // 129*128
#define KBLKS 134         // af k-blocks of 32
#define MBLKS 32          // 512/16
#define KSTEPS32 134      // k-steps of 32 (covers 4288; A=0 past 4224)
#define PANEL_CLAMP 2163184u  // 4225*512 - 16 : last safe 16B source in a W1 panel

typedef __attribute__((ext_vector_type(8))) short bf16x8;
typedef __attribute__((ext_vector_type(4))) float f32x4;
typedef __attribute__((ext_vector_type(4))) unsigned int u32x4;

__device__ __forceinline__ unsigned short f2bf(float f){
    unsigned u = __builtin_bit_cast(unsigned, f);
    unsigned r = (u + 0x7FFFu + ((u >> 16) & 1u)) >> 16;   // RNE
    return (unsigned short)r;
}
__device__ __forceinline__ unsigned pack2(float a, float b){
    return (unsigned)f2bf(a) | ((unsigned)f2bf(b) << 16);
}

__device__ __forceinline__ void gload16(const void* g, void* l){
    __builtin_amdgcn_global_load_lds(
        (const __attribute__((address_space(1))) unsigned int*)g,
        (__attribute__((address_space(3))) unsigned int*)l, 16, 0, 0);
}

// ---------------- K1: build VA (bf16) in MFMA A-fragment granule order --------
__global__ void build_af(const float* __restrict__ audio,
                         const float* __restrict__ video,
                         uint4* __restrict__ af)
{
    int gid = blockIdx.x * 256 + threadIdx.x;
    if (gid >= KBLKS * MBLKS * 64) return;
    int lane = gid & 63;
    int mblk = (gid >> 6) & 31;
    int kblk = gid >> 11;
    int m  = mblk * 16 + (lane & 15);
    int k0 = kblk * 32 + (lane >> 4) * 8;
    float vals[8];
#pragma unroll
    for (int j = 0; j < 8; ++j){
        int k = k0 + j;
        float p = 0.f;
        if (k < NJK){
            int jj = k / 65;
            int kk = k - jj * 65;
            float a = (kk == 0) ? 1.f : audio[m * 64 + kk - 1];
            float v = (jj == 0) ? 1.f : video[m * 64 + jj - 1];
            p = a * v;
        }
        vals[j] = p;
    }
    uint4 o;
    o.x = pack2(vals[0], vals[1]);
    o.y = pack2(vals[2], vals[3]);
    o.z = pack2(vals[4], vals[5]);
    o.w = pack2(vals[6], vals[7]);
    af[gid] = o;
}

// ---------------- K2: fused Z = VA @ bf16(W1')  -------------------------------
// 128x128 tile, BK=32, grid 516, 4 waves (2x2 of 64x64 per k-step of 32).
// All staging via global_load_lds (async, unsinkable). Per iter:
//   bar0 | STAGE(ks+1) | vmcnt(6) bar1 | CONVERT raw[p]->frag[p] | lgkm0 bar2 |
//   MFMA from A[p]+frag[p].  Raw s_barrier + counted vmcnt: no vmcnt(0) drain.
// LDS: A dbuf 2x8K @0 | raw fp32 dbuf 2x16K @16K | frag bf16 dbuf 2x8K @48K.
__global__ __launch_bounds__(256, 2) void fusion_gemm(
    const float* __restrict__ W1,
    const uint4* __restrict__ af,
    float* __restrict__ Z)
{
    __shared__ __align__(16) char lds[65536];

    // bijective XCD swizzle (nwg=516: q=64, r=4)
    int orig = blockIdx.x;
    int xcd  = orig & 7;
    int base = (xcd < 4) ? xcd * 65 : 260 + (xcd - 4) * 64;
    int w    = base + (orig >> 3);
    int nt = w >> 2;          // 0..128
    int mt = w & 3;           // 0..3

    int t    = threadIdx.x;
    int lane = t & 63;
    int wv   = t >> 6;
    int wm   = wv >> 1, wn = wv & 1;

    f32x4 acc[4][4] = {};

    const char* wpanel = (const char*)(W1 + (size_t)nt * (NJK * 128));
    const char* afb    = (const char*)af;

    int n_c = t & 127;        // convert: this thread's n-column
    int kg  = t >> 7;         // 0/1 : k-half (16 rows)

#define STAGE(ks_, pb_)                                                         \
    do {                                                                        \
        char* dstA_ = lds + (pb_) * 8192;                                       \
        char* dstB_ = lds + 16384 + (pb_) * 16384;                              \
        _Pragma("unroll")                                                       \
        for (int i_ = 0; i_ < 6; ++i_){                                         \
            int c_ = wv * 6 + i_;                                               \
            if (c_ < 8){                                                        \
                const char* s_ = afb + (size_t)(ks_) * 32768                    \
                               + (size_t)(mt * 8 + c_) * 1024 + lane * 16;      \
                gload16(s_, dstA_ + c_ * 1024);                                 \
            } else {                                                            \
                unsigned bo_ = (unsigned)(ks_) * 16384u                         \
                             + (unsigned)(c_ - 8) * 1024u + (unsigned)lane * 16u;\
                if (bo_ > PANEL_CLAMP) bo_ = PANEL_CLAMP;  /* tail-safe */      \
                gload16(wpanel + bo_, dstB_ + (c_ - 8) * 1024);                 \
            }                                                                   \
        }                                                                       \
    } while (0)

    // prologue: stage tile 0
    STAGE(0, 0);

    for (int ks = 0; ks < KSTEPS32; ++ks){
        int p = ks & 1;

        __builtin_amdgcn_s_barrier();            // bar0: prev MFMA done, bufs[!p] free
        if (ks + 1 < KSTEPS32){
            STAGE(ks + 1, p ^ 1);
            asm volatile("s_waitcnt vmcnt(6)" ::: "memory");   // tile ks arrived
        } else {
            asm volatile("s_waitcnt vmcnt(0)" ::: "memory");
        }
        __builtin_amdgcn_s_barrier();            // bar1: raw[p]/A[p] visible to all

        // ---- CONVERT: raw[p] fp32 [32k][128n] -> frag[p] bf16 [n][32k] swizzled
        {
            const char* rawp = lds + 16384 + p * 16384;
            char* fragp      = lds + 49152 + p * 8192;
            float v[16];
#pragma unroll
            for (int j = 0; j < 16; ++j)
                v[j] = *(const float*)(rawp + (kg * 16 + j) * 512 + n_c * 4);
            u32x4 u0, u1;
            u0.x = pack2(v[0],  v[1]);  u0.y = pack2(v[2],  v[3]);
            u0.z = pack2(v[4],  v[5]);  u0.w = pack2(v[6],  v[7]);
            u1.x = pack2(v[8],  v[9]);  u1.y = pack2(v[10], v[11]);
            u1.z = pack2(v[12], v[13]); u1.w = pack2(v[14], v[15]);
            int swz = ((n_c >> 1) & 3) << 4;
            *(u32x4*)(fragp + ((n_c * 64 + kg * 32     ) ^ swz)) = u0;
            *(u32x4*)(fragp + ((n_c * 64 + kg * 32 + 16) ^ swz)) = u1;
        }
        asm volatile("s_waitcnt lgkmcnt(0)" ::: "memory");
        __builtin_amdgcn_s_barrier();            // bar2: frag[p] ready

        // ---- MFMA from A[p] (linear granules) + frag[p]
        {
            const char* sa = lds + p * 8192;
            const char* sf = lds + 49152 + p * 8192;
            bf16x8 a[4], b[4];
#pragma unroll
            for (int f = 0; f < 4; ++f)
                a[f] = *(const bf16x8*)(sa + (wm * 4 + f) * 1024 + lane * 16);
#pragma unroll
            for (int g = 0; g < 4; ++g){
                int nr = wn * 64 + g * 16 + (lane & 15);
                int byte = (nr * 64 + (lane >> 4) * 16) ^ (((nr >> 1) & 3) << 4);
                b[g] = *(const bf16x8*)(sf + byte);
            }
#pragma unroll
            for (int f = 0; f < 4; ++f)
#pragma unroll
                for (int g = 0; g < 4; ++g)
                    acc[f][g] = __builtin_amdgcn_mfma_f32_16x16x32_bf16(a[f], b[g], acc[f][g], 0, 0, 0);
        }
    }

    // epilogue: D layout col=lane&15, row=(lane>>4)*4+reg
    int row0 = mt * 128 + wm * 64 + (lane >> 4) * 4;
    int col0 = nt * 128 + wn * 64 + (lane & 15);
#pragma unroll
    for (int f = 0; f < 4; ++f)
#pragma unroll
        for (int g = 0; g < 4; ++g)
#pragma unroll
            for (int r = 0; r < 4; ++r)
                Z[(size_t)(row0 + f * 16 + r) * NTOT + col0 + g * 16] = acc[f][g][r];
}

// ---------------- K3: y1 = relu(b1 + sum_i t1_i * Z[:,i,:]); y2; sigmoid head --
__global__ void tail_mlp(const float* __restrict__ Z,
                         const float* __restrict__ text,
                         const float* __restrict__ b1,
                         const float* __restrict__ W2,
                         const float* __restrict__ b2,
                         const float* __restrict__ W3,
                         const float* __restrict__ b3,
                         float* __restrict__ out)
{
    int b   = blockIdx.x;     // 512
    int tid = threadIdx.x;    // 128
    __shared__ float t1s[NI];
    __shared__ float y1s[POST];
    __shared__ float red[2];

    t1s[tid + 1] = text[b * 128 + tid];
    if (tid == 0) t1s[0] = 1.f;
    __syncthreads();

    const float* zrow = Z + (size_t)b * NTOT;
    float acc = 0.f;
    for (int i = 0; i < NI; ++i)
        acc = fmaf(t1s[i], zrow[i * 128 + tid], acc);
    acc += b1[tid];
    float y1 = fmaxf(acc, 0.f);
    y1s[tid] = y1;
    __syncthreads();

    float a2 = b2[tid];
    for (int q = 0; q < 128; ++q)
        a2 = fmaf(y1s[q], W2[q * 128 + tid], a2);
    float y2 = fmaxf(a2, 0.f);

    float part = y2 * W3[tid];
#pragma unroll
    for (int off = 32; off > 0; off >>= 1)
        part += __shfl_down(part, off);
    if ((tid & 63) == 0) red[tid >> 6] = part;
    __syncthreads();
    if (tid == 0){
        float z = red[0] + red[1] + b3[0];
        out[b] = 6.f / (1.f + expf(-z)) - 3.f;
    }
}

extern "C" void kernel_launch(void* const* d_in, const int* in_sizes, int n_in,
                              void* d_out, int out_size, void* d_ws, size_t ws_size,
                              hipStream_t stream)
{
    const float* audio = (const float*)d_in[0];
    const float* video = (const float*)d_in[1];
    const float* text  = (const float*)d_in[2];
    const float* W1    = (const float*)d_in[3];
    const float* b1    = (const float*)d_in[4];
    const float* W2    = (const float*)d_in[5];
    const float* b2    = (const float*)d_in[6];
    const float* W3    = (const float*)d_in[7];
    const float* b3    = (const float*)d_in[8];
    float* out = (float*)d_out;

    char* ws = (char*)d_ws;
    uint4* af = (uint4*)ws;                       // 4,390,912 B
    float* Z  = (float*)(ws + (8u << 20));        // 33,816,576 B

    int af_granules = KBLKS * MBLKS * 64;         // 274432 threads
    build_af<<<(af_granules + 255) / 256, 256, 0, stream>>>(audio, video, af);
    fusion_gemm<<<516, 256, 0, stream>>>(W1, af, Z);
    tail_mlp<<<512, 128, 0, stream>>>(Z, text, b1, W2, b2, W3, b3, out);
}

// Round 12
// 155.990 us; speedup vs baseline: 1.7262x; 1.7262x over previous
//
#include <hip/hip_runtime.h>
#include <hip/hip_bf16.h>
#include <math.h>

#define POST 128
#define NI 129            // T+1
#define NJK 4225          // 65*65
#define NTOT 16512        // 129*128
#define KBLKS 134         // af k-blocks of 32
#define MBLKS 32          // 512/16
#define KSTEPS32 133      // k-steps of 32 (covers k<4256; A=0 past 4224)
#define PANEL_CLAMP 2163184u  // 4225*512 - 16 : last safe 16B source in a W1 panel

typedef __attribute__((ext_vector_type(8))) short bf16x8;
typedef __attribute__((ext_vector_type(4))) float f32x4;
typedef __attribute__((ext_vector_type(4))) unsigned int u32x4;

__device__ __forceinline__ unsigned short f2bf(float f){
    unsigned u = __builtin_bit_cast(unsigned, f);
    unsigned r = (u + 0x7FFFu + ((u >> 16) & 1u)) >> 16;   // RNE
    return (unsigned short)r;
}
__device__ __forceinline__ unsigned pack2(float a, float b){
    return (unsigned)f2bf(a) | ((unsigned)f2bf(b) << 16);
}
__device__ __forceinline__ unsigned cvtpk(float lo, float hi){
    unsigned r;
    asm("v_cvt_pk_bf16_f32 %0, %1, %2" : "=v"(r) : "v"(lo), "v"(hi));
    return r;   // bf16(lo) in [15:0], bf16(hi) in [31:16]
}

__device__ __forceinline__ void gload16(const void* g, void* l){
    __builtin_amdgcn_global_load_lds(
        (const __attribute__((address_space(1))) unsigned int*)g,
        (__attribute__((address_space(3))) unsigned int*)l, 16, 0, 0);
}

// ---------------- K1: build VA (bf16) in MFMA A-fragment granule order --------
// granule (kblk, mblk): 64 lanes x 16B; element (l,j): m=mblk*16+(l&15),
// k = kblk*32 + (l>>4)*8 + j. Zero-padded past NJK (k=4224 is last real row).
__global__ void build_af(const float* __restrict__ audio,
                         const float* __restrict__ video,
                         uint4* __restrict__ af)
{
    int gid = blockIdx.x * 256 + threadIdx.x;
    if (gid >= KBLKS * MBLKS * 64) return;
    int lane = gid & 63;
    int mblk = (gid >> 6) & 31;
    int kblk = gid >> 11;
    int m  = mblk * 16 + (lane & 15);
    int k0 = kblk * 32 + (lane >> 4) * 8;
    float vals[8];
#pragma unroll
    for (int j = 0; j < 8; ++j){
        int k = k0 + j;
        float p = 0.f;
        if (k < NJK){
            int jj = k / 65;
            int kk = k - jj * 65;
            float a = (kk == 0) ? 1.f : audio[m * 64 + kk - 1];
            float v = (jj == 0) ? 1.f : video[m * 64 + jj - 1];
            p = a * v;
        }
        vals[j] = p;
    }
    uint4 o;
    o.x = pack2(vals[0], vals[1]);
    o.y = pack2(vals[2], vals[3]);
    o.z = pack2(vals[4], vals[5]);
    o.w = pack2(vals[6], vals[7]);
    af[gid] = o;
}

// ---------------- K2: fused Z = VA @ bf16(W1')  -------------------------------
// 128x128 tile, BK=32, grid 516 = 4 mt x 129 nt, 4 waves (2x2 of 64x64).
// All staging via global_load_lds. B raw fp32 staged with SOURCE-swizzled
// granules (G21): granule (k,ng) lives at LDS col ng ^ (((k>>3)&1)<<2) ->
// fragment reads are 2-way (free). Convert at fragment-read via v_cvt_pk.
// Loop: STAGE(ks+1) | vmcnt(6) | s_barrier | compute | s_barrier  (no drain).
__global__ __launch_bounds__(256, 3) void fusion_gemm(
    const float* __restrict__ W1,
    const uint4* __restrict__ af,
    float* __restrict__ Z)
{
    __shared__ __align__(16) char lds[49152];
    // [0,16K): A bf16 dbuf (2x8K) | [16K,48K): B raw fp32 dbuf (2x16K)

    // bijective XCD swizzle (nwg=516: q=64, r=4)
    int orig = blockIdx.x;
    int xcd  = orig & 7;
    int base = (xcd < 4) ? xcd * 65 : 260 + (xcd - 4) * 64;
    int w    = base + (orig >> 3);
    int nt = w >> 2;          // 0..128
    int mt = w & 3;           // 0..3

    int t    = threadIdx.x;
    int lane = t & 63;
    int wv   = t >> 6;
    int wm   = wv >> 1, wn = wv & 1;

    f32x4 acc[4][4] = {};

    const char* wpanel = (const char*)(W1 + (size_t)nt * (NJK * 128));
    const char* afb    = (const char*)af;

    // B staging source swizzle (involution): k = 2*cb + (lane>>5),
    // ng_src = (lane&31) ^ (((k>>3)&1)<<2); LDS dest stays linear.
#define STAGE(ks_, pb_)                                                         \
    do {                                                                        \
        char* dstA_ = lds + (pb_) * 8192;                                       \
        char* dstB_ = lds + 16384 + (pb_) * 16384;                              \
        _Pragma("unroll")                                                       \
        for (int i_ = 0; i_ < 6; ++i_){                                         \
            int c_ = wv * 6 + i_;                                               \
            if (c_ < 8){                                                        \
                const char* s_ = afb + (size_t)(ks_) * 32768                    \
                               + (size_t)(mt * 8 + c_) * 1024 + lane * 16;      \
                gload16(s_, dstA_ + c_ * 1024);                                 \
            } else {                                                            \
                int cb_ = c_ - 8;                                               \
                int k_  = 2 * cb_ + (lane >> 5);                                \
                int ngs_ = (lane & 31) ^ (((k_ >> 3) & 1) << 2);                \
                unsigned bo_ = (unsigned)(ks_) * 16384u                         \
                             + (unsigned)k_ * 512u + (unsigned)ngs_ * 16u;      \
                if (bo_ > PANEL_CLAMP) bo_ = PANEL_CLAMP;  /* tail-safe */      \
                gload16(wpanel + bo_, dstB_ + cb_ * 1024);                      \
            }                                                                   \
        }                                                                       \
    } while (0)

    // prologue: stage tile 0
    STAGE(0, 0);

    for (int ks = 0; ks < KSTEPS32; ++ks){
        int p = ks & 1;

        if (ks + 1 < KSTEPS32){
            STAGE(ks + 1, p ^ 1);                            // 6 loads/wave in flight
            asm volatile("s_waitcnt vmcnt(6)" ::: "memory"); // tile ks arrived
        } else {
            asm volatile("s_waitcnt vmcnt(0)" ::: "memory");
        }
        __builtin_amdgcn_s_barrier();            // tile ks visible to all waves

        // ---- compute from buf p
        {
            const char* sa   = lds + p * 8192;
            const char* rawp = lds + 16384 + p * 16384;

            bf16x8 a[4], b[4];
#pragma unroll
            for (int f = 0; f < 4; ++f)
                a[f] = *(const bf16x8*)(sa + (wm * 4 + f) * 1024 + lane * 16);

            int h  = lane >> 4;                  // k-group 0..3 (k = h*8+j)
            int fx = (h & 1) << 2;               // read-side swizzle
#pragma unroll
            for (int g = 0; g < 4; ++g){
                int n = wn * 64 + g * 16 + (lane & 15);
                const char* bp = rawp + (h * 8) * 512
                               + (((n >> 2) ^ fx) * 16) + (n & 3) * 4;
                float v[8];
#pragma unroll
                for (int j = 0; j < 8; ++j)
                    v[j] = *(const float*)(bp + j * 512);
                u32x4 ub;
                ub.x = cvtpk(v[0], v[1]);
                ub.y = cvtpk(v[2], v[3]);
                ub.z = cvtpk(v[4], v[5]);
                ub.w = cvtpk(v[6], v[7]);
                b[g] = __builtin_bit_cast(bf16x8, ub);
            }

#pragma unroll
            for (int f = 0; f < 4; ++f)
#pragma unroll
                for (int g = 0; g < 4; ++g)
                    acc[f][g] = __builtin_amdgcn_mfma_f32_16x16x32_bf16(a[f], b[g], acc[f][g], 0, 0, 0);
        }

        __builtin_amdgcn_sched_barrier(0);
        __builtin_amdgcn_s_barrier();            // all waves done reading buf p
    }

    // epilogue: D layout col=lane&15, row=(lane>>4)*4+reg
    int row0 = mt * 128 + wm * 64 + (lane >> 4) * 4;
    int col0 = nt * 128 + wn * 64 + (lane & 15);
#pragma unroll
    for (int f = 0; f < 4; ++f)
#pragma unroll
        for (int g = 0; g < 4; ++g)
#pragma unroll
            for (int r = 0; r < 4; ++r)
                Z[(size_t)(row0 + f * 16 + r) * NTOT + col0 + g * 16] = acc[f][g][r];
}

// ---------------- K3: y1 = relu(b1 + sum_i t1_i * Z[:,i,:]); y2; sigmoid head --
__global__ void tail_mlp(const float* __restrict__ Z,
                         const float* __restrict__ text,
                         const float* __restrict__ b1,
                         const float* __restrict__ W2,
                         const float* __restrict__ b2,
                         const float* __restrict__ W3,
                         const float* __restrict__ b3,
                         float* __restrict__ out)
{
    int b   = blockIdx.x;     // 512
    int tid = threadIdx.x;    // 128
    __shared__ float t1s[NI];
    __shared__ float y1s[POST];
    __shared__ float red[2];

    t1s[tid + 1] = text[b * 128 + tid];
    if (tid == 0) t1s[0] = 1.f;
    __syncthreads();

    const float* zrow = Z + (size_t)b * NTOT;
    float acc = 0.f;
    for (int i = 0; i < NI; ++i)
        acc = fmaf(t1s[i], zrow[i * 128 + tid], acc);
    acc += b1[tid];
    float y1 = fmaxf(acc, 0.f);
    y1s[tid] = y1;
    __syncthreads();

    float a2 = b2[tid];
    for (int q = 0; q < 128; ++q)
        a2 = fmaf(y1s[q], W2[q * 128 + tid], a2);
    float y2 = fmaxf(a2, 0.f);

    float part = y2 * W3[tid];
#pragma unroll
    for (int off = 32; off > 0; off >>= 1)
        part += __shfl_down(part, off);
    if ((tid & 63) == 0) red[tid >> 6] = part;
    __syncthreads();
    if (tid == 0){
        float z = red[0] + red[1] + b3[0];
        out[b] = 6.f / (1.f + expf(-z)) - 3.f;
    }
}

extern "C" void kernel_launch(void* const* d_in, const int* in_sizes, int n_in,
                              void* d_out, int out_size, void* d_ws, size_t ws_size,
                              hipStream_t stream)
{
    const float* audio = (const float*)d_in[0];
    const float* video = (const float*)d_in[1];
    const float* text  = (const float*)d_in[2];
    const float* W1    = (const float*)d_in[3];
    const float* b1    = (const float*)d_in[4];
    const float* W2    = (const float*)d_in[5];
    const float* b2    = (const float*)d_in[6];
    const float* W3    = (const float*)d_in[7];
    const float* b3    = (const float*)d_in[8];
    float* out = (float*)d_out;

    char* ws = (char*)d_ws;
    uint4* af = (uint4*)ws;                       // 4,390,912 B
    float* Z  = (float*)(ws + (8u << 20));        // 33,816,576 B

    int af_granules = KBLKS * MBLKS * 64;         // 274432 threads
    build_af<<<(af_granules + 255) / 256, 256, 0, stream>>>(audio, video, af);
    fusion_gemm<<<516, 256, 0, stream>>>(W1, af, Z);
    tail_mlp<<<512, 128, 0, stream>>>(Z, text, b1, W2, b2, W3, b3, out);
}